// Round 3
// baseline (716.375 us; speedup 1.0000x reference)
//
#include <hip/hip_runtime.h>
#include <math.h>

#define VOCAB 50000
#define DD 200
#define AA 32
#define RR 30000
#define LL 40
#define BB 10000

static __device__ __forceinline__ float bflo(unsigned int u) {
    return __uint_as_float(u << 16);
}
static __device__ __forceinline__ float bfhi(unsigned int u) {
    return __uint_as_float(u & 0xFFFF0000u);
}

// ---------------------------------------------------------------------------
// Kernel 0: convert emb table f32 -> bf16 (RNE). 10M elements, streaming.
// ---------------------------------------------------------------------------
__global__ __launch_bounds__(256) void cvt_bf16_kernel(
    const float* __restrict__ src, unsigned short* __restrict__ dst, int n4)
{
    int i = blockIdx.x * 256 + threadIdx.x;
    if (i >= n4) return;
    float4 f = ((const float4*)src)[i];
    ushort4 u;
    {
        unsigned int x;
        x = __float_as_uint(f.x); u.x = (unsigned short)((x + 0x7FFFu + ((x >> 16) & 1u)) >> 16);
        x = __float_as_uint(f.y); u.y = (unsigned short)((x + 0x7FFFu + ((x >> 16) & 1u)) >> 16);
        x = __float_as_uint(f.z); u.z = (unsigned short)((x + 0x7FFFu + ((x >> 16) & 1u)) >> 16);
        x = __float_as_uint(f.w); u.w = (unsigned short)((x + 0x7FFFu + ((x >> 16) & 1u)) >> 16);
    }
    ((ushort4*)dst)[i] = u;
}

// ---------------------------------------------------------------------------
// Kernel 1: V = Y @ W_M   ([R,D] @ [D,D] -> [R,D])
// ---------------------------------------------------------------------------
__global__ __launch_bounds__(256) void v_gemm_kernel(
    const float* __restrict__ Y, const float* __restrict__ WM,
    float* __restrict__ V)
{
    __shared__ float yt[32 * DD];
    const int r0 = blockIdx.x * 32;
    const int tid = threadIdx.x;

    for (int i = tid; i < 32 * DD; i += 256) {
        int j = i / DD, e = i - j * DD;
        int r = r0 + j;
        yt[i] = (r < RR) ? Y[r * DD + e] : 0.f;
    }
    __syncthreads();

    if (tid < DD) {
        float acc[32];
        #pragma unroll
        for (int j = 0; j < 32; ++j) acc[j] = 0.f;
        for (int e = 0; e < DD; ++e) {
            float w = WM[e * DD + tid];
            #pragma unroll
            for (int j = 0; j < 32; ++j) acc[j] += yt[j * DD + e] * w;
        }
        #pragma unroll
        for (int j = 0; j < 32; ++j) {
            int r = r0 + j;
            if (r < RR) V[r * DD + tid] = acc[j];
        }
    }
}

// ---------------------------------------------------------------------------
// Kernel 2: per-review attention -> p_t [R, A].
// All-register e_w: wave w owns words [10w, 10w+10); lane i<50 holds cols
// 4i..4i+3 as one uint2 (4 bf16). All 10 gathers + V row + hist issued
// up-front -> deep MLP. Only dx (40 f) and partial z (4x200 f) cross waves.
// ---------------------------------------------------------------------------
__global__ __launch_bounds__(256, 8) void attn_kernel(
    const int* __restrict__ hist, const unsigned short* __restrict__ emb16,
    const float* __restrict__ V, const float* __restrict__ WW,
    const float* __restrict__ bW, float* __restrict__ PT)
{
    __shared__ float dxs[LL];
    __shared__ float zss[4][DD];   // 3200 B

    const int r = blockIdx.x;
    const int tid = threadIdx.x;
    const int wave = tid >> 6, lane = tid & 63;

    // each wave redundantly loads hist row (160 B, L1/L2-hot) and V row
    int h = (lane < LL) ? hist[r * LL + lane] : 0;
    float4 v4 = make_float4(0.f, 0.f, 0.f, 0.f);
    if (lane < 50) v4 = ((const float4*)(V + (size_t)r * DD))[lane];

    // issue all 10 word-row gathers (8 B/lane, 400 B/word, contiguous)
    uint2 e[10];
    #pragma unroll
    for (int j = 0; j < 10; ++j) {
        int w = __shfl(h, wave * 10 + j);
        e[j] = (lane < 50) ? ((const uint2*)(emb16 + (size_t)w * DD))[lane]
                           : make_uint2(0u, 0u);
    }

    // dx[l] = e_w[l] . v
    #pragma unroll
    for (int j = 0; j < 10; ++j) {
        float p = 0.f;
        if (lane < 50)
            p = bflo(e[j].x) * v4.x + bfhi(e[j].x) * v4.y
              + bflo(e[j].y) * v4.z + bfhi(e[j].y) * v4.w;
        #pragma unroll
        for (int off = 32; off; off >>= 1) p += __shfl_xor(p, off);
        if (lane == 0) dxs[wave * 10 + j] = p;
    }
    __syncthreads();

    // softmax over L=40, computed redundantly per wave (in-register)
    float x = (lane < LL) ? dxs[lane] : -INFINITY;
    float m = x;
    #pragma unroll
    for (int off = 32; off; off >>= 1) m = fmaxf(m, __shfl_xor(m, off));
    float ex = (lane < LL) ? __expf(x - m) : 0.f;
    float s = ex;
    #pragma unroll
    for (int off = 32; off; off >>= 1) s += __shfl_xor(s, off);
    float axl = ex / s;            // lane l holds ax[l]

    // partial z for this wave's 10 words (in-register)
    float4 z = make_float4(0.f, 0.f, 0.f, 0.f);
    #pragma unroll
    for (int j = 0; j < 10; ++j) {
        float a = __shfl(axl, wave * 10 + j);
        z.x += a * bflo(e[j].x);
        z.y += a * bfhi(e[j].x);
        z.z += a * bflo(e[j].y);
        z.w += a * bfhi(e[j].y);
    }
    if (lane < 50) ((float4*)zss[wave])[lane] = z;
    __syncthreads();

    // p_t[r][a] = z . W_W[a] + b_W[a]   (8 threads per aspect)
    {
        int a = tid >> 3, j = tid & 7;
        float acc = 0.f;
        #pragma unroll 5
        for (int d = j; d < DD; d += 8) {
            float zd = zss[0][d] + zss[1][d] + zss[2][d] + zss[3][d];
            acc += zd * WW[a * DD + d];
        }
        #pragma unroll
        for (int off = 4; off; off >>= 1) acc += __shfl_xor(acc, off);
        if (j == 0) PT[r * AA + a] = acc + bW[a];
    }
}

// ---------------------------------------------------------------------------
// Kernel 3: both sparse [B,R] @ p_t [R,A] in one launch.
// 8 lanes per nnz; lane j loads PT float4 and does 4 consecutive atomics.
// ---------------------------------------------------------------------------
__global__ __launch_bounds__(256) void spmm_kernel(
    const int* __restrict__ uidx, const float* __restrict__ uval,
    const int* __restrict__ iidx, const float* __restrict__ ival,
    const float* __restrict__ PT, float* __restrict__ out, int nnz)
{
    int g = blockIdx.x * 256 + threadIdx.x;
    int n = g >> 3;
    const int* idx = uidx;
    const float* val = uval;
    float* o = (float*)out;
    if (n >= nnz) {            // second matrix
        n -= nnz;
        if (n >= nnz) return;
        idx = iidx; val = ival; o += BB * AA;
    }
    int j = g & 7;
    int row = idx[n];
    int col = idx[nnz + n];
    float w = val[n];
    float4 p = ((const float4*)(PT + (size_t)col * AA))[j];
    float* dst = o + row * AA + 4 * j;
    atomicAdd(dst + 0, w * p.x);
    atomicAdd(dst + 1, w * p.y);
    atomicAdd(dst + 2, w * p.z);
    atomicAdd(dst + 3, w * p.w);
}

extern "C" void kernel_launch(void* const* d_in, const int* in_sizes, int n_in,
                              void* d_out, int out_size, void* d_ws, size_t ws_size,
                              hipStream_t stream) {
    const int*   hist = (const int*)d_in[0];
    const float* ypos = (const float*)d_in[1];
    const int*   uidx = (const int*)d_in[3];
    const float* uval = (const float*)d_in[4];
    const int*   iidx = (const int*)d_in[5];
    const float* ival = (const float*)d_in[6];
    const float* emb  = (const float*)d_in[8];
    const float* WM   = (const float*)d_in[9];
    const float* WW   = (const float*)d_in[10];
    const float* bW   = (const float*)d_in[11];

    unsigned short* emb16 = (unsigned short*)d_ws;            // [VOCAB, D] bf16, 20 MB
    float* V  = (float*)(emb16 + (size_t)VOCAB * DD);         // [R, D]  24 MB
    float* PT = V + (size_t)RR * DD;                          // [R, A]  3.84 MB
    float* out = (float*)d_out;                               // [2, B, A]

    const int nnz = in_sizes[4];

    hipMemsetAsync(d_out, 0, (size_t)out_size * sizeof(float), stream);

    cvt_bf16_kernel<<<(VOCAB * DD / 4 + 255) / 256, 256, 0, stream>>>(
        emb, emb16, VOCAB * DD / 4);
    v_gemm_kernel<<<(RR + 31) / 32, 256, 0, stream>>>(ypos, WM, V);
    attn_kernel<<<RR, 256, 0, stream>>>(hist, emb16, V, WW, bW, PT);

    const int spmm_blocks = (2 * nnz * 8 + 255) / 256;
    spmm_kernel<<<spmm_blocks, 256, 0, stream>>>(uidx, uval, iidx, ival, PT, out, nnz);
}

// Round 4
// 360.296 us; speedup vs baseline: 1.9883x; 1.9883x over previous
//
#include <hip/hip_runtime.h>
#include <math.h>

#define VOCAB 50000
#define DD 200
#define AA 32
#define RR 30000
#define LL 40
#define BB 10000

static __device__ __forceinline__ float bf2f(unsigned short u) {
    return __uint_as_float((unsigned int)u << 16);
}

// ---------------------------------------------------------------------------
// Kernel 0: convert emb table f32 -> bf16 (RNE). 10M elements, streaming.
// ---------------------------------------------------------------------------
__global__ __launch_bounds__(256) void cvt_bf16_kernel(
    const float* __restrict__ src, unsigned short* __restrict__ dst, int n4)
{
    int i = blockIdx.x * 256 + threadIdx.x;
    if (i >= n4) return;
    float4 f = ((const float4*)src)[i];
    ushort4 u;
    {
        unsigned int x;
        x = __float_as_uint(f.x); u.x = (unsigned short)((x + 0x7FFFu + ((x >> 16) & 1u)) >> 16);
        x = __float_as_uint(f.y); u.y = (unsigned short)((x + 0x7FFFu + ((x >> 16) & 1u)) >> 16);
        x = __float_as_uint(f.z); u.z = (unsigned short)((x + 0x7FFFu + ((x >> 16) & 1u)) >> 16);
        x = __float_as_uint(f.w); u.w = (unsigned short)((x + 0x7FFFu + ((x >> 16) & 1u)) >> 16);
    }
    ((ushort4*)dst)[i] = u;
}

// ---------------------------------------------------------------------------
// Kernel 1: V = Y @ W_M   ([R,D] @ [D,D] -> [R,D])
// ---------------------------------------------------------------------------
__global__ __launch_bounds__(256) void v_gemm_kernel(
    const float* __restrict__ Y, const float* __restrict__ WM,
    float* __restrict__ V)
{
    __shared__ float yt[32 * DD];
    const int r0 = blockIdx.x * 32;
    const int tid = threadIdx.x;

    for (int i = tid; i < 32 * DD; i += 256) {
        int j = i / DD, e = i - j * DD;
        int r = r0 + j;
        yt[i] = (r < RR) ? Y[r * DD + e] : 0.f;
    }
    __syncthreads();

    if (tid < DD) {
        float acc[32];
        #pragma unroll
        for (int j = 0; j < 32; ++j) acc[j] = 0.f;
        for (int e = 0; e < DD; ++e) {
            float w = WM[e * DD + tid];
            #pragma unroll
            for (int j = 0; j < 32; ++j) acc[j] += yt[j * DD + e] * w;
        }
        #pragma unroll
        for (int j = 0; j < 32; ++j) {
            int r = r0 + j;
            if (r < RR) V[r * DD + tid] = acc[j];
        }
    }
}

// ---------------------------------------------------------------------------
// Kernel 2: per-review attention -> p_t [R, A].  bf16 e_w staged in LDS.
// Staging: 1000 uint4 chunks (40 rows x 25); each thread owns chunks
// {tid, tid+256, tid+512, tid+768}, loads the 4 hist words directly from
// global (no widx LDS round-trip, no extra barrier), issues 4 independent
// hist->gather->ds_write chains.  LDS ~18 KB -> 8 blocks/CU.
// ---------------------------------------------------------------------------
__global__ __launch_bounds__(256, 8) void attn_kernel(
    const int* __restrict__ hist, const unsigned short* __restrict__ emb16,
    const float* __restrict__ V, const float* __restrict__ WW,
    const float* __restrict__ bW, float* __restrict__ PT)
{
    __shared__ __align__(16) unsigned short ew[LL * DD];  // 16000 B (bf16)
    __shared__ __align__(16) float v[DD];                 // 800 B
    __shared__ float zs[DD];                              // 800 B
    __shared__ float dxs[LL];
    __shared__ float ax[LL];

    const int r = blockIdx.x;
    const int tid = threadIdx.x;
    const int* hrow = hist + r * LL;

    // ---- staging: all loads issued up-front -------------------------------
    const int i0 = tid, i1 = tid + 256, i2 = tid + 512, i3 = tid + 768;
    const int l0 = i0 / 25, c0 = i0 - 25 * l0;
    const int l1 = i1 / 25, c1 = i1 - 25 * l1;
    const int l2 = i2 / 25, c2 = i2 - 25 * l2;
    const int l3 = i3 / 25, c3 = i3 - 25 * l3;
    const bool has3 = (i3 < LL * 25);

    int w0 = hrow[l0];
    int w1 = hrow[l1];
    int w2 = hrow[l2];
    int w3 = has3 ? hrow[l3] : 0;

    uint4 q0 = ((const uint4*)(emb16 + (size_t)w0 * DD))[c0];
    uint4 q1 = ((const uint4*)(emb16 + (size_t)w1 * DD))[c1];
    uint4 q2 = ((const uint4*)(emb16 + (size_t)w2 * DD))[c2];
    uint4 q3 = has3 ? ((const uint4*)(emb16 + (size_t)w3 * DD))[c3]
                    : make_uint4(0u, 0u, 0u, 0u);
    float4 vv = make_float4(0.f, 0.f, 0.f, 0.f);
    if (tid < 50) vv = ((const float4*)(V + (size_t)r * DD))[tid];

    ((uint4*)ew)[i0] = q0;
    ((uint4*)ew)[i1] = q1;
    ((uint4*)ew)[i2] = q2;
    if (has3) ((uint4*)ew)[i3] = q3;
    if (tid < 50) ((float4*)v)[tid] = vv;
    __syncthreads();

    const int wave = tid >> 6, lane = tid & 63;

    // dx[l] = e_w[l] . v   (wave per word; lanes 0..49 cover 4 elems each)
    for (int l = wave; l < LL; l += 4) {
        float p = 0.f;
        if (lane < 50) {
            int d0 = lane * 4;
            ushort4 e4 = *(const ushort4*)(ew + l * DD + d0);
            float4  v4 = *(const float4*)(v + d0);
            p = bf2f(e4.x) * v4.x + bf2f(e4.y) * v4.y
              + bf2f(e4.z) * v4.z + bf2f(e4.w) * v4.w;
        }
        #pragma unroll
        for (int off = 32; off; off >>= 1) p += __shfl_xor(p, off);
        if (lane == 0) dxs[l] = p;
    }
    __syncthreads();

    // softmax over L=40 in wave 0
    if (wave == 0) {
        float x = (lane < LL) ? dxs[lane] : -INFINITY;
        float m = x;
        #pragma unroll
        for (int off = 32; off; off >>= 1) m = fmaxf(m, __shfl_xor(m, off));
        float e = (lane < LL) ? __expf(x - m) : 0.f;
        float s = e;
        #pragma unroll
        for (int off = 32; off; off >>= 1) s += __shfl_xor(s, off);
        if (lane < LL) ax[lane] = e / s;
    }
    __syncthreads();

    // z_s[d] = sum_l ax[l] * e_w[l][d]
    if (tid < DD) {
        float acc = 0.f;
        #pragma unroll 8
        for (int l = 0; l < LL; ++l) acc += ax[l] * bf2f(ew[l * DD + tid]);
        zs[tid] = acc;
    }
    __syncthreads();

    // p_t[r][a] = z_s . W_W[a] + b_W[a]   (8 threads per aspect)
    {
        int a = tid >> 3, j = tid & 7;
        float acc = 0.f;
        for (int d = j; d < DD; d += 8) acc += zs[d] * WW[a * DD + d];
        #pragma unroll
        for (int off = 4; off; off >>= 1) acc += __shfl_xor(acc, off);
        if (j == 0) PT[r * AA + a] = acc + bW[a];
    }
}

// ---------------------------------------------------------------------------
// Kernel 3: sparse [B,R] @ p_t [R,A] via gather + atomicAdd scatter.
// 32 lanes per nnz entry (one lane per aspect column, coalesced atomics).
// ---------------------------------------------------------------------------
__global__ __launch_bounds__(256) void spmm_kernel(
    const int* __restrict__ idx, const float* __restrict__ val,
    const float* __restrict__ PT, float* __restrict__ out, int nnz)
{
    int g = blockIdx.x * 256 + threadIdx.x;
    int n = g >> 5;
    if (n >= nnz) return;
    int a = g & 31;
    int row = idx[n];          // index[0][n]
    int col = idx[nnz + n];    // index[1][n]
    float w = val[n];
    atomicAdd(&out[row * AA + a], w * PT[col * AA + a]);
}

extern "C" void kernel_launch(void* const* d_in, const int* in_sizes, int n_in,
                              void* d_out, int out_size, void* d_ws, size_t ws_size,
                              hipStream_t stream) {
    const int*   hist = (const int*)d_in[0];
    const float* ypos = (const float*)d_in[1];
    const int*   uidx = (const int*)d_in[3];
    const float* uval = (const float*)d_in[4];
    const int*   iidx = (const int*)d_in[5];
    const float* ival = (const float*)d_in[6];
    const float* emb  = (const float*)d_in[8];
    const float* WM   = (const float*)d_in[9];
    const float* WW   = (const float*)d_in[10];
    const float* bW   = (const float*)d_in[11];

    unsigned short* emb16 = (unsigned short*)d_ws;            // [VOCAB, D] bf16, 20 MB
    float* V  = (float*)(emb16 + (size_t)VOCAB * DD);         // [R, D]  24 MB
    float* PT = V + (size_t)RR * DD;                          // [R, A]  3.84 MB
    float* out = (float*)d_out;                               // [2, B, A]

    const int nnz = in_sizes[4];

    hipMemsetAsync(d_out, 0, (size_t)out_size * sizeof(float), stream);

    cvt_bf16_kernel<<<(VOCAB * DD / 4 + 255) / 256, 256, 0, stream>>>(
        emb, emb16, VOCAB * DD / 4);
    v_gemm_kernel<<<(RR + 31) / 32, 256, 0, stream>>>(ypos, WM, V);
    attn_kernel<<<RR, 256, 0, stream>>>(hist, emb16, V, WW, bW, PT);

    const int spmm_blocks = (nnz * 32 + 255) / 256;
    spmm_kernel<<<spmm_blocks, 256, 0, stream>>>(uidx, uval, PT, out, nnz);
    spmm_kernel<<<spmm_blocks, 256, 0, stream>>>(iidx, ival, PT, out + BB * AA, nnz);
}

// Round 5
// 328.857 us; speedup vs baseline: 2.1784x; 1.0956x over previous
//
#include <hip/hip_runtime.h>
#include <math.h>

#define VOCAB 50000
#define DD 200
#define AA 32
#define RR 30000
#define LL 40
#define BB 10000

typedef _Float16 half2_t __attribute__((ext_vector_type(2)));

static __device__ __forceinline__ unsigned short f2h(float f) {
    return __builtin_bit_cast(unsigned short, (_Float16)f);   // RNE
}
static __device__ __forceinline__ float h2f(unsigned short u) {
    return (float)__builtin_bit_cast(_Float16, u);
}
// packed f16 dot2: acc += a.lo*b.lo + a.hi*b.hi
static __device__ __forceinline__ float dot2(unsigned int a, unsigned int b, float acc) {
#if __has_builtin(__builtin_amdgcn_fdot2)
    return __builtin_amdgcn_fdot2(__builtin_bit_cast(half2_t, a),
                                  __builtin_bit_cast(half2_t, b), acc, false);
#else
    return acc + h2f((unsigned short)(a & 0xFFFF)) * h2f((unsigned short)(b & 0xFFFF))
               + h2f((unsigned short)(a >> 16))    * h2f((unsigned short)(b >> 16));
#endif
}

// ---------------------------------------------------------------------------
// Kernel 0: convert emb table f32 -> f16 (RNE). 10M elements, streaming.
// ---------------------------------------------------------------------------
__global__ __launch_bounds__(256) void cvt_f16_kernel(
    const float* __restrict__ src, unsigned short* __restrict__ dst, int n4)
{
    int i = blockIdx.x * 256 + threadIdx.x;
    if (i >= n4) return;
    float4 f = ((const float4*)src)[i];
    ushort4 u;
    u.x = f2h(f.x); u.y = f2h(f.y); u.z = f2h(f.z); u.w = f2h(f.w);
    ((ushort4*)dst)[i] = u;
}

// ---------------------------------------------------------------------------
// Kernel 1: V = Y @ W_M, output packed f16 pairs: V16[r][i] = (d=2i lo, 2i+1 hi)
// ---------------------------------------------------------------------------
__global__ __launch_bounds__(256) void v_gemm_kernel(
    const float* __restrict__ Y, const float* __restrict__ WM,
    unsigned int* __restrict__ V16)
{
    __shared__ float yt[32 * DD];
    const int r0 = blockIdx.x * 32;
    const int tid = threadIdx.x;

    for (int i = tid; i < 32 * DD; i += 256) {
        int j = i / DD, e = i - j * DD;
        int r = r0 + j;
        yt[i] = (r < RR) ? Y[r * DD + e] : 0.f;
    }
    __syncthreads();

    if (tid < DD) {
        float acc[32];
        #pragma unroll
        for (int j = 0; j < 32; ++j) acc[j] = 0.f;
        for (int e = 0; e < DD; ++e) {
            float w = WM[e * DD + tid];
            #pragma unroll
            for (int j = 0; j < 32; ++j) acc[j] += yt[j * DD + e] * w;
        }
        #pragma unroll
        for (int j = 0; j < 32; ++j) {
            float partner = __shfl_xor(acc[j], 1);
            int r = r0 + j;
            if (r < RR && (tid & 1) == 0) {
                unsigned int lo = f2h(acc[j]);
                unsigned int hi = f2h(partner);
                V16[(size_t)r * (DD / 2) + (tid >> 1)] = lo | (hi << 16);
            }
        }
    }
}

// ---------------------------------------------------------------------------
// Kernel 2: per-review attention -> p_t [R, A].  f16 e_w staged in LDS.
// dx: 2 words/iter (half-wave each), 8 dims/lane, fdot2, 5-step reduce.
// ---------------------------------------------------------------------------
__global__ __launch_bounds__(256, 8) void attn_kernel(
    const int* __restrict__ hist, const unsigned short* __restrict__ emb16,
    const unsigned int* __restrict__ V16, const float* __restrict__ WW,
    const float* __restrict__ bW, float* __restrict__ PT)
{
    __shared__ __align__(16) unsigned short ew[LL * DD];  // 16000 B (f16)
    __shared__ __align__(16) unsigned int vp[DD / 2];     // 400 B packed f16
    __shared__ float zs[DD];                              // 800 B
    __shared__ float dxs[LL];
    __shared__ float ax[LL];

    const int r = blockIdx.x;
    const int tid = threadIdx.x;
    const int* hrow = hist + r * LL;

    // ---- staging: all loads issued up-front -------------------------------
    const int i0 = tid, i1 = tid + 256, i2 = tid + 512, i3 = tid + 768;
    const int l0 = i0 / 25, c0 = i0 - 25 * l0;
    const int l1 = i1 / 25, c1 = i1 - 25 * l1;
    const int l2 = i2 / 25, c2 = i2 - 25 * l2;
    const int l3 = i3 / 25, c3 = i3 - 25 * l3;
    const bool has3 = (i3 < LL * 25);

    int w0 = hrow[l0];
    int w1 = hrow[l1];
    int w2 = hrow[l2];
    int w3 = has3 ? hrow[l3] : 0;

    uint4 q0 = ((const uint4*)(emb16 + (size_t)w0 * DD))[c0];
    uint4 q1 = ((const uint4*)(emb16 + (size_t)w1 * DD))[c1];
    uint4 q2 = ((const uint4*)(emb16 + (size_t)w2 * DD))[c2];
    uint4 q3 = has3 ? ((const uint4*)(emb16 + (size_t)w3 * DD))[c3]
                    : make_uint4(0u, 0u, 0u, 0u);
    uint4 vv = make_uint4(0u, 0u, 0u, 0u);
    if (tid < 25) vv = ((const uint4*)(V16 + (size_t)r * (DD / 2)))[tid];

    ((uint4*)ew)[i0] = q0;
    ((uint4*)ew)[i1] = q1;
    ((uint4*)ew)[i2] = q2;
    if (has3) ((uint4*)ew)[i3] = q3;
    if (tid < 25) ((uint4*)vp)[tid] = vv;
    __syncthreads();

    const int wave = tid >> 6, lane = tid & 63;
    const int half = lane >> 5, s = lane & 31;

    // hoist this lane's v chunk (dims 8s..8s+7) into registers
    uint4 vq = (s < 25) ? ((const uint4*)vp)[s] : make_uint4(0u, 0u, 0u, 0u);

    // dx: wave w owns words 10w..10w+9; 2 words per iteration
    #pragma unroll
    for (int j = 0; j < 5; ++j) {
        const int l = wave * 10 + 2 * j + half;
        float p = 0.f;
        if (s < 25) {
            uint4 eq = *(const uint4*)(ew + l * DD + s * 8);
            p = dot2(eq.x, vq.x, p);
            p = dot2(eq.y, vq.y, p);
            p = dot2(eq.z, vq.z, p);
            p = dot2(eq.w, vq.w, p);
        }
        #pragma unroll
        for (int off = 16; off; off >>= 1) p += __shfl_xor(p, off);
        if (s == 0) dxs[l] = p;
    }
    __syncthreads();

    // softmax over L=40 in wave 0
    if (wave == 0) {
        float x = (lane < LL) ? dxs[lane] : -INFINITY;
        float m = x;
        #pragma unroll
        for (int off = 32; off; off >>= 1) m = fmaxf(m, __shfl_xor(m, off));
        float e = (lane < LL) ? __expf(x - m) : 0.f;
        float sum = e;
        #pragma unroll
        for (int off = 32; off; off >>= 1) sum += __shfl_xor(sum, off);
        if (lane < LL) ax[lane] = e / sum;
    }
    __syncthreads();

    // z_s[d] = sum_l ax[l] * e_w[l][d]
    if (tid < DD) {
        float acc = 0.f;
        #pragma unroll 8
        for (int l = 0; l < LL; ++l) acc += ax[l] * h2f(ew[l * DD + tid]);
        zs[tid] = acc;
    }
    __syncthreads();

    // p_t[r][a] = z_s . W_W[a] + b_W[a]   (8 threads per aspect)
    {
        int a = tid >> 3, j = tid & 7;
        float acc = 0.f;
        for (int d = j; d < DD; d += 8) acc += zs[d] * WW[a * DD + d];
        #pragma unroll
        for (int off = 4; off; off >>= 1) acc += __shfl_xor(acc, off);
        if (j == 0) PT[r * AA + a] = acc + bW[a];
    }
}

// ---------------------------------------------------------------------------
// Kernel 3: both sparse [B,R] @ p_t [R,A] in one launch.
// 32 lanes per nnz entry (one lane per aspect column, coalesced atomics).
// ---------------------------------------------------------------------------
__global__ __launch_bounds__(256) void spmm_kernel(
    const int* __restrict__ uidx, const float* __restrict__ uval,
    const int* __restrict__ iidx, const float* __restrict__ ival,
    const float* __restrict__ PT, float* __restrict__ out, int nnz)
{
    int g = blockIdx.x * 256 + threadIdx.x;
    int n = g >> 5;
    const int* idx = uidx;
    const float* val = uval;
    float* o = out;
    if (n >= nnz) {            // second matrix
        n -= nnz;
        if (n >= nnz) return;
        idx = iidx; val = ival; o += BB * AA;
    }
    int a = g & 31;
    int row = idx[n];          // index[0][n]
    int col = idx[nnz + n];    // index[1][n]
    float w = val[n];
    atomicAdd(&o[row * AA + a], w * PT[col * AA + a]);
}

extern "C" void kernel_launch(void* const* d_in, const int* in_sizes, int n_in,
                              void* d_out, int out_size, void* d_ws, size_t ws_size,
                              hipStream_t stream) {
    const int*   hist = (const int*)d_in[0];
    const float* ypos = (const float*)d_in[1];
    const int*   uidx = (const int*)d_in[3];
    const float* uval = (const float*)d_in[4];
    const int*   iidx = (const int*)d_in[5];
    const float* ival = (const float*)d_in[6];
    const float* emb  = (const float*)d_in[8];
    const float* WM   = (const float*)d_in[9];
    const float* WW   = (const float*)d_in[10];
    const float* bW   = (const float*)d_in[11];

    unsigned short* emb16 = (unsigned short*)d_ws;            // [VOCAB, D] f16, 20 MB
    unsigned int* V16 = (unsigned int*)(emb16 + (size_t)VOCAB * DD); // [R, D/2] packed, 12 MB
    float* PT = (float*)(V16 + (size_t)RR * (DD / 2));        // [R, A]  3.84 MB
    float* out = (float*)d_out;                               // [2, B, A]

    const int nnz = in_sizes[4];

    hipMemsetAsync(d_out, 0, (size_t)out_size * sizeof(float), stream);

    cvt_f16_kernel<<<(VOCAB * DD / 4 + 255) / 256, 256, 0, stream>>>(
        emb, emb16, VOCAB * DD / 4);
    v_gemm_kernel<<<(RR + 31) / 32, 256, 0, stream>>>(ypos, WM, V16);
    attn_kernel<<<RR, 256, 0, stream>>>(hist, emb16, V16, WW, bW, PT);

    const int spmm_blocks = (2 * nnz * 32 + 255) / 256;
    spmm_kernel<<<spmm_blocks, 256, 0, stream>>>(uidx, uval, iidx, ival, PT, out, nnz);
}

// Round 6
// 296.435 us; speedup vs baseline: 2.4166x; 1.1094x over previous
//
#include <hip/hip_runtime.h>
#include <math.h>

#define VOCAB 50000
#define DD 200
#define AA 32
#define RR 30000
#define LL 40
#define BB 10000

typedef _Float16 half2_t __attribute__((ext_vector_type(2)));

static __device__ __forceinline__ unsigned short f2h(float f) {
    return __builtin_bit_cast(unsigned short, (_Float16)f);   // RNE
}
static __device__ __forceinline__ float hlo(unsigned int u) {
    return (float)__builtin_bit_cast(_Float16, (unsigned short)(u & 0xFFFFu));
}
static __device__ __forceinline__ float hhi(unsigned int u) {
    return (float)__builtin_bit_cast(_Float16, (unsigned short)(u >> 16));
}
static __device__ __forceinline__ unsigned int pkh(float lo, float hi) {
    return (unsigned int)f2h(lo) | ((unsigned int)f2h(hi) << 16);
}
// packed f16 dot2: acc += a.lo*b.lo + a.hi*b.hi
static __device__ __forceinline__ float dot2(unsigned int a, unsigned int b, float acc) {
#if __has_builtin(__builtin_amdgcn_fdot2)
    return __builtin_amdgcn_fdot2(__builtin_bit_cast(half2_t, a),
                                  __builtin_bit_cast(half2_t, b), acc, false);
#else
    return acc + hlo(a) * hlo(b) + hhi(a) * hhi(b);
#endif
}

// ---------------------------------------------------------------------------
// Kernel 0: convert emb table f32 -> f16 (RNE). 10M elements, streaming.
// ---------------------------------------------------------------------------
__global__ __launch_bounds__(256) void cvt_f16_kernel(
    const float* __restrict__ src, unsigned short* __restrict__ dst, int n4)
{
    int i = blockIdx.x * 256 + threadIdx.x;
    if (i >= n4) return;
    float4 f = ((const float4*)src)[i];
    ushort4 u;
    u.x = f2h(f.x); u.y = f2h(f.y); u.z = f2h(f.z); u.w = f2h(f.w);
    ((ushort4*)dst)[i] = u;
}

// ---------------------------------------------------------------------------
// Kernel 0b: pack WM pairs along e: WMP[e2*200+d] = (WM[2e2][d], WM[2e2+1][d])
// ---------------------------------------------------------------------------
__global__ __launch_bounds__(256) void wmp_kernel(
    const float* __restrict__ WM, unsigned int* __restrict__ WMP)
{
    int i = blockIdx.x * 256 + threadIdx.x;
    if (i >= (DD / 2) * DD) return;
    int e2 = i / DD, d = i - e2 * DD;
    WMP[i] = pkh(WM[(2 * e2) * DD + d], WM[(2 * e2 + 1) * DD + d]);
}

// ---------------------------------------------------------------------------
// Kernel 1: V = Y @ W_M  with f16 dot2. Y staged as packed f16 in LDS
// (cvt on the fly). Output packed f16 pairs V16[r][i] = (d=2i, d=2i+1).
// ---------------------------------------------------------------------------
__global__ __launch_bounds__(256) void v_gemm_kernel(
    const float* __restrict__ Y, const unsigned int* __restrict__ WMP,
    unsigned int* __restrict__ V16)
{
    __shared__ unsigned int yt[32 * (DD / 2)];   // 12.8 KB packed f16
    const int r0 = blockIdx.x * 32;
    const int tid = threadIdx.x;

    for (int i = tid; i < 32 * 50; i += 256) {   // 50 float4 chunks per row
        int j = i / 50, c = i - 50 * j;
        int r = r0 + j;
        float4 f = (r < RR) ? ((const float4*)(Y + (size_t)r * DD))[c]
                            : make_float4(0.f, 0.f, 0.f, 0.f);
        uint2 u = make_uint2(pkh(f.x, f.y), pkh(f.z, f.w));
        ((uint2*)yt)[i] = u;
    }
    __syncthreads();

    if (tid < DD) {
        float acc[32];
        #pragma unroll
        for (int j = 0; j < 32; ++j) acc[j] = 0.f;
        for (int e2 = 0; e2 < DD / 2; e2 += 2) {
            unsigned int w0 = WMP[e2 * DD + tid];        // coalesced
            unsigned int w1 = WMP[(e2 + 1) * DD + tid];
            #pragma unroll
            for (int j = 0; j < 32; ++j) {
                uint2 y2 = *(const uint2*)(yt + j * (DD / 2) + e2); // broadcast b64
                acc[j] = dot2(y2.x, w0, acc[j]);
                acc[j] = dot2(y2.y, w1, acc[j]);
            }
        }
        #pragma unroll
        for (int j = 0; j < 32; ++j) {
            float partner = __shfl_xor(acc[j], 1);
            int r = r0 + j;
            if (r < RR && (tid & 1) == 0)
                V16[(size_t)r * (DD / 2) + (tid >> 1)] =
                    pkh(acc[j], partner);
        }
    }
}

// ---------------------------------------------------------------------------
// Kernel 2: per-review attention -> p_t [R, A].  NO e_w LDS: each lane
// gathers its 5 word-chunks (uint4 = 8 f16 dims) straight to registers.
// Wave w owns words 10w..10w+9; lane (half,s): words 2j+half, dims 8s..8s+7.
// z accumulated in-register, combined across halves by shuffle.
// ---------------------------------------------------------------------------
__global__ __launch_bounds__(256, 8) void attn_kernel(
    const int* __restrict__ hist, const unsigned short* __restrict__ emb16,
    const unsigned int* __restrict__ V16, const float* __restrict__ WW,
    const float* __restrict__ bW, float* __restrict__ PT)
{
    __shared__ float dxs[LL];
    __shared__ float zss[4][DD];   // 3200 B
    __shared__ float zs[DD];       // 800 B

    const int r = blockIdx.x;
    const int tid = threadIdx.x;
    const int wave = tid >> 6, lane = tid & 63;
    const int half = lane >> 5, s = lane & 31;
    const bool act = (s < 25);

    // hist row (lane<40) and this lane's V chunk (dims 8s..8s+7, per-wave)
    int h = (lane < LL) ? hist[r * LL + lane] : 0;
    uint4 vq = make_uint4(0u, 0u, 0u, 0u);
    if (act) vq = ((const uint4*)(V16 + (size_t)r * (DD / 2)))[s];

    // direct register gathers: word l = wave*10 + 2j + half, j=0..4
    uint4 e0, e1, e2, e3, e4;
    const uint4 zq = make_uint4(0u, 0u, 0u, 0u);
    {
        int w;
        w = __shfl(h, wave * 10 + 0 + half);
        e0 = act ? ((const uint4*)(emb16 + (size_t)w * DD))[s] : zq;
        w = __shfl(h, wave * 10 + 2 + half);
        e1 = act ? ((const uint4*)(emb16 + (size_t)w * DD))[s] : zq;
        w = __shfl(h, wave * 10 + 4 + half);
        e2 = act ? ((const uint4*)(emb16 + (size_t)w * DD))[s] : zq;
        w = __shfl(h, wave * 10 + 6 + half);
        e3 = act ? ((const uint4*)(emb16 + (size_t)w * DD))[s] : zq;
        w = __shfl(h, wave * 10 + 8 + half);
        e4 = act ? ((const uint4*)(emb16 + (size_t)w * DD))[s] : zq;
    }

    // dx for this lane's 5 words: dot over 8 dims then 5-step 32-wide reduce
    #define DX(EJ, J)                                                        \
    {                                                                        \
        float p = 0.f;                                                       \
        p = dot2(EJ.x, vq.x, p); p = dot2(EJ.y, vq.y, p);                    \
        p = dot2(EJ.z, vq.z, p); p = dot2(EJ.w, vq.w, p);                    \
        _Pragma("unroll")                                                    \
        for (int off = 16; off; off >>= 1) p += __shfl_xor(p, off);          \
        if (s == 0) dxs[wave * 10 + 2 * (J) + half] = p;                     \
    }
    DX(e0, 0) DX(e1, 1) DX(e2, 2) DX(e3, 3) DX(e4, 4)
    #undef DX
    __syncthreads();

    // softmax over L=40, redundant per wave (lane l holds ax[l])
    float x = (lane < LL) ? dxs[lane] : -INFINITY;
    float m = x;
    #pragma unroll
    for (int off = 32; off; off >>= 1) m = fmaxf(m, __shfl_xor(m, off));
    float ex = (lane < LL) ? __expf(x - m) : 0.f;
    float sum = ex;
    #pragma unroll
    for (int off = 32; off; off >>= 1) sum += __shfl_xor(sum, off);
    float axl = ex / sum;

    // z partial in registers: 8 dims per lane over this lane's 5 words
    float z0 = 0.f, z1 = 0.f, z2 = 0.f, z3 = 0.f,
          z4 = 0.f, z5 = 0.f, z6 = 0.f, z7 = 0.f;
    #define ZACC(EJ, J)                                                      \
    {                                                                        \
        float a = __shfl(axl, wave * 10 + 2 * (J) + half);                   \
        z0 += a * hlo(EJ.x); z1 += a * hhi(EJ.x);                            \
        z2 += a * hlo(EJ.y); z3 += a * hhi(EJ.y);                            \
        z4 += a * hlo(EJ.z); z5 += a * hhi(EJ.z);                            \
        z6 += a * hlo(EJ.w); z7 += a * hhi(EJ.w);                            \
    }
    ZACC(e0, 0) ZACC(e1, 1) ZACC(e2, 2) ZACC(e3, 3) ZACC(e4, 4)
    #undef ZACC
    // combine the two halves (word 2j+0 and 2j+1 live in half 0/1)
    z0 += __shfl_xor(z0, 32); z1 += __shfl_xor(z1, 32);
    z2 += __shfl_xor(z2, 32); z3 += __shfl_xor(z3, 32);
    z4 += __shfl_xor(z4, 32); z5 += __shfl_xor(z5, 32);
    z6 += __shfl_xor(z6, 32); z7 += __shfl_xor(z7, 32);
    if (half == 0 && act) {
        ((float4*)zss[wave])[2 * s]     = make_float4(z0, z1, z2, z3);
        ((float4*)zss[wave])[2 * s + 1] = make_float4(z4, z5, z6, z7);
    }
    __syncthreads();

    // sum wave partials
    if (tid < DD) zs[tid] = zss[0][tid] + zss[1][tid] + zss[2][tid] + zss[3][tid];
    __syncthreads();

    // p_t[r][a] = z_s . W_W[a] + b_W[a]   (8 threads per aspect)
    {
        int a = tid >> 3, j = tid & 7;
        float acc = 0.f;
        for (int d = j; d < DD; d += 8) acc += zs[d] * WW[a * DD + d];
        #pragma unroll
        for (int off = 4; off; off >>= 1) acc += __shfl_xor(acc, off);
        if (j == 0) PT[r * AA + a] = acc + bW[a];
    }
}

// ---------------------------------------------------------------------------
// Kernel 3: both sparse [B,R] @ p_t [R,A] in one launch.
// 32 lanes per nnz entry (one lane per aspect column, coalesced atomics).
// ---------------------------------------------------------------------------
__global__ __launch_bounds__(256) void spmm_kernel(
    const int* __restrict__ uidx, const float* __restrict__ uval,
    const int* __restrict__ iidx, const float* __restrict__ ival,
    const float* __restrict__ PT, float* __restrict__ out, int nnz)
{
    int g = blockIdx.x * 256 + threadIdx.x;
    int n = g >> 5;
    const int* idx = uidx;
    const float* val = uval;
    float* o = out;
    if (n >= nnz) {            // second matrix
        n -= nnz;
        if (n >= nnz) return;
        idx = iidx; val = ival; o += BB * AA;
    }
    int a = g & 31;
    int row = idx[n];          // index[0][n]
    int col = idx[nnz + n];    // index[1][n]
    float w = val[n];
    atomicAdd(&o[row * AA + a], w * PT[col * AA + a]);
}

extern "C" void kernel_launch(void* const* d_in, const int* in_sizes, int n_in,
                              void* d_out, int out_size, void* d_ws, size_t ws_size,
                              hipStream_t stream) {
    const int*   hist = (const int*)d_in[0];
    const float* ypos = (const float*)d_in[1];
    const int*   uidx = (const int*)d_in[3];
    const float* uval = (const float*)d_in[4];
    const int*   iidx = (const int*)d_in[5];
    const float* ival = (const float*)d_in[6];
    const float* emb  = (const float*)d_in[8];
    const float* WM   = (const float*)d_in[9];
    const float* WW   = (const float*)d_in[10];
    const float* bW   = (const float*)d_in[11];

    unsigned short* emb16 = (unsigned short*)d_ws;                   // 20 MB
    unsigned int* WMP = (unsigned int*)(emb16 + (size_t)VOCAB * DD); // 80 KB
    unsigned int* V16 = WMP + (DD / 2) * DD;                         // 12 MB
    float* PT = (float*)(V16 + (size_t)RR * (DD / 2));               // 3.84 MB
    float* out = (float*)d_out;                                      // [2, B, A]

    const int nnz = in_sizes[4];

    hipMemsetAsync(d_out, 0, (size_t)out_size * sizeof(float), stream);

    cvt_f16_kernel<<<(VOCAB * DD / 4 + 255) / 256, 256, 0, stream>>>(
        emb, emb16, VOCAB * DD / 4);
    wmp_kernel<<<((DD / 2) * DD + 255) / 256, 256, 0, stream>>>(WM, WMP);
    v_gemm_kernel<<<(RR + 31) / 32, 256, 0, stream>>>(ypos, WMP, V16);
    attn_kernel<<<RR, 256, 0, stream>>>(hist, emb16, V16, WW, bW, PT);

    const int spmm_blocks = (2 * nnz * 32 + 255) / 256;
    spmm_kernel<<<spmm_blocks, 256, 0, stream>>>(uidx, uval, iidx, ival, PT, out, nnz);
}

// Round 7
// 296.374 us; speedup vs baseline: 2.4171x; 1.0002x over previous
//
#include <hip/hip_runtime.h>
#include <math.h>

#define VOCAB 50000
#define DD 200
#define AA 32
#define RR 30000
#define LL 40
#define BB 10000

typedef _Float16 half2_t __attribute__((ext_vector_type(2)));

static __device__ __forceinline__ unsigned short f2h(float f) {
    return __builtin_bit_cast(unsigned short, (_Float16)f);   // RNE
}
static __device__ __forceinline__ float hlo(unsigned int u) {
    return (float)__builtin_bit_cast(_Float16, (unsigned short)(u & 0xFFFFu));
}
static __device__ __forceinline__ float hhi(unsigned int u) {
    return (float)__builtin_bit_cast(_Float16, (unsigned short)(u >> 16));
}
static __device__ __forceinline__ unsigned int pkh(float lo, float hi) {
    return (unsigned int)f2h(lo) | ((unsigned int)f2h(hi) << 16);
}
// packed f16 dot2: acc += a.lo*b.lo + a.hi*b.hi
static __device__ __forceinline__ float dot2(unsigned int a, unsigned int b, float acc) {
#if __has_builtin(__builtin_amdgcn_fdot2)
    return __builtin_amdgcn_fdot2(__builtin_bit_cast(half2_t, a),
                                  __builtin_bit_cast(half2_t, b), acc, false);
#else
    return acc + hlo(a) * hlo(b) + hhi(a) * hhi(b);
#endif
}

// ---------------------------------------------------------------------------
// Kernel 0: convert emb table f32 -> f16 (RNE). 10M elements, streaming.
// ---------------------------------------------------------------------------
__global__ __launch_bounds__(256) void cvt_f16_kernel(
    const float* __restrict__ src, unsigned short* __restrict__ dst, int n4)
{
    int i = blockIdx.x * 256 + threadIdx.x;
    if (i >= n4) return;
    float4 f = ((const float4*)src)[i];
    ushort4 u;
    u.x = f2h(f.x); u.y = f2h(f.y); u.z = f2h(f.z); u.w = f2h(f.w);
    ((ushort4*)dst)[i] = u;
}

// ---------------------------------------------------------------------------
// Kernel 0b: pack WM pairs along e: WMP[e2*200+d] = (WM[2e2][d], WM[2e2+1][d])
// ---------------------------------------------------------------------------
__global__ __launch_bounds__(256) void wmp_kernel(
    const float* __restrict__ WM, unsigned int* __restrict__ WMP)
{
    int i = blockIdx.x * 256 + threadIdx.x;
    if (i >= (DD / 2) * DD) return;
    int e2 = i / DD, d = i - e2 * DD;
    WMP[i] = pkh(WM[(2 * e2) * DD + d], WM[(2 * e2 + 1) * DD + d]);
}

// ---------------------------------------------------------------------------
// Kernel 1: V = Y @ W_M  with f16 dot2. Y staged as packed f16 in LDS
// (cvt on the fly). Output packed f16 pairs V16[r][i] = (d=2i, d=2i+1).
// ---------------------------------------------------------------------------
__global__ __launch_bounds__(256) void v_gemm_kernel(
    const float* __restrict__ Y, const unsigned int* __restrict__ WMP,
    unsigned int* __restrict__ V16)
{
    __shared__ unsigned int yt[32 * (DD / 2)];   // 12.8 KB packed f16
    const int r0 = blockIdx.x * 32;
    const int tid = threadIdx.x;

    for (int i = tid; i < 32 * 50; i += 256) {   // 50 float4 chunks per row
        int j = i / 50, c = i - 50 * j;
        int r = r0 + j;
        float4 f = (r < RR) ? ((const float4*)(Y + (size_t)r * DD))[c]
                            : make_float4(0.f, 0.f, 0.f, 0.f);
        uint2 u = make_uint2(pkh(f.x, f.y), pkh(f.z, f.w));
        ((uint2*)yt)[i] = u;
    }
    __syncthreads();

    if (tid < DD) {
        float acc[32];
        #pragma unroll
        for (int j = 0; j < 32; ++j) acc[j] = 0.f;
        for (int e2 = 0; e2 < DD / 2; e2 += 2) {
            unsigned int w0 = WMP[e2 * DD + tid];        // coalesced
            unsigned int w1 = WMP[(e2 + 1) * DD + tid];
            #pragma unroll
            for (int j = 0; j < 32; ++j) {
                uint2 y2 = *(const uint2*)(yt + j * (DD / 2) + e2); // broadcast b64
                acc[j] = dot2(y2.x, w0, acc[j]);
                acc[j] = dot2(y2.y, w1, acc[j]);
            }
        }
        #pragma unroll
        for (int j = 0; j < 32; ++j) {
            float partner = __shfl_xor(acc[j], 1);
            int r = r0 + j;
            if (r < RR && (tid & 1) == 0)
                V16[(size_t)r * (DD / 2) + (tid >> 1)] =
                    pkh(acc[j], partner);
        }
    }
}

// ---------------------------------------------------------------------------
// Kernel 2: per-review attention -> p_t [R, A].  NO e_w LDS: each lane
// gathers its 5 word-chunks (uint4 = 8 f16 dims) straight to registers.
// Wave w owns words 10w..10w+9; lane (half,s): words 2j+half, dims 8s..8s+7.
// launch_bounds(256,6): VGPR cap ~85 so the 5 e-vectors stay resident
// (R6's (256,8) pin caused a 124 MB scratch spill).
// ---------------------------------------------------------------------------
__global__ __launch_bounds__(256, 6) void attn_kernel(
    const int* __restrict__ hist, const unsigned short* __restrict__ emb16,
    const unsigned int* __restrict__ V16, const float* __restrict__ WW,
    const float* __restrict__ bW, float* __restrict__ PT)
{
    __shared__ float dxs[LL];
    __shared__ float zss[4][DD];   // 3200 B
    __shared__ float zs[DD];       // 800 B

    const int r = blockIdx.x;
    const int tid = threadIdx.x;
    const int wave = tid >> 6, lane = tid & 63;
    const int half = lane >> 5, s = lane & 31;
    const bool act = (s < 25);

    // hist row (lane<40) and this lane's V chunk (dims 8s..8s+7, per-wave)
    int h = (lane < LL) ? hist[r * LL + lane] : 0;
    uint4 vq = make_uint4(0u, 0u, 0u, 0u);
    if (act) vq = ((const uint4*)(V16 + (size_t)r * (DD / 2)))[s];

    // direct register gathers: word l = wave*10 + 2j + half, j=0..4
    uint4 e0, e1, e2, e3, e4;
    const uint4 zq = make_uint4(0u, 0u, 0u, 0u);
    {
        int w;
        w = __shfl(h, wave * 10 + 0 + half);
        e0 = act ? ((const uint4*)(emb16 + (size_t)w * DD))[s] : zq;
        w = __shfl(h, wave * 10 + 2 + half);
        e1 = act ? ((const uint4*)(emb16 + (size_t)w * DD))[s] : zq;
        w = __shfl(h, wave * 10 + 4 + half);
        e2 = act ? ((const uint4*)(emb16 + (size_t)w * DD))[s] : zq;
        w = __shfl(h, wave * 10 + 6 + half);
        e3 = act ? ((const uint4*)(emb16 + (size_t)w * DD))[s] : zq;
        w = __shfl(h, wave * 10 + 8 + half);
        e4 = act ? ((const uint4*)(emb16 + (size_t)w * DD))[s] : zq;
    }

    // dx for this lane's 5 words: dot over 8 dims then 5-step 32-wide reduce
    #define DX(EJ, J)                                                        \
    {                                                                        \
        float p = 0.f;                                                       \
        p = dot2(EJ.x, vq.x, p); p = dot2(EJ.y, vq.y, p);                    \
        p = dot2(EJ.z, vq.z, p); p = dot2(EJ.w, vq.w, p);                    \
        _Pragma("unroll")                                                    \
        for (int off = 16; off; off >>= 1) p += __shfl_xor(p, off);          \
        if (s == 0) dxs[wave * 10 + 2 * (J) + half] = p;                     \
    }
    DX(e0, 0) DX(e1, 1) DX(e2, 2) DX(e3, 3) DX(e4, 4)
    #undef DX
    __syncthreads();

    // softmax over L=40, redundant per wave (lane l holds ax[l])
    float x = (lane < LL) ? dxs[lane] : -INFINITY;
    float m = x;
    #pragma unroll
    for (int off = 32; off; off >>= 1) m = fmaxf(m, __shfl_xor(m, off));
    float ex = (lane < LL) ? __expf(x - m) : 0.f;
    float sum = ex;
    #pragma unroll
    for (int off = 32; off; off >>= 1) sum += __shfl_xor(sum, off);
    float axl = ex / sum;

    // z partial in registers: 8 dims per lane over this lane's 5 words
    float z0 = 0.f, z1 = 0.f, z2 = 0.f, z3 = 0.f,
          z4 = 0.f, z5 = 0.f, z6 = 0.f, z7 = 0.f;
    #define ZACC(EJ, J)                                                      \
    {                                                                        \
        float a = __shfl(axl, wave * 10 + 2 * (J) + half);                   \
        z0 += a * hlo(EJ.x); z1 += a * hhi(EJ.x);                            \
        z2 += a * hlo(EJ.y); z3 += a * hhi(EJ.y);                            \
        z4 += a * hlo(EJ.z); z5 += a * hhi(EJ.z);                            \
        z6 += a * hlo(EJ.w); z7 += a * hhi(EJ.w);                            \
    }
    ZACC(e0, 0) ZACC(e1, 1) ZACC(e2, 2) ZACC(e3, 3) ZACC(e4, 4)
    #undef ZACC
    // combine the two halves (word 2j+0 and 2j+1 live in half 0/1)
    z0 += __shfl_xor(z0, 32); z1 += __shfl_xor(z1, 32);
    z2 += __shfl_xor(z2, 32); z3 += __shfl_xor(z3, 32);
    z4 += __shfl_xor(z4, 32); z5 += __shfl_xor(z5, 32);
    z6 += __shfl_xor(z6, 32); z7 += __shfl_xor(z7, 32);
    if (half == 0 && act) {
        ((float4*)zss[wave])[2 * s]     = make_float4(z0, z1, z2, z3);
        ((float4*)zss[wave])[2 * s + 1] = make_float4(z4, z5, z6, z7);
    }
    __syncthreads();

    // sum wave partials
    if (tid < DD) zs[tid] = zss[0][tid] + zss[1][tid] + zss[2][tid] + zss[3][tid];
    __syncthreads();

    // p_t[r][a] = z_s . W_W[a] + b_W[a]   (8 threads per aspect)
    {
        int a = tid >> 3, j = tid & 7;
        float acc = 0.f;
        for (int d = j; d < DD; d += 8) acc += zs[d] * WW[a * DD + d];
        #pragma unroll
        for (int off = 4; off; off >>= 1) acc += __shfl_xor(acc, off);
        if (j == 0) PT[r * AA + a] = acc + bW[a];
    }
}

// ---------------------------------------------------------------------------
// Kernel 3: both sparse [B,R] @ p_t [R,A] in one launch.
// 32 lanes per nnz entry (one lane per aspect column, coalesced atomics).
// ---------------------------------------------------------------------------
__global__ __launch_bounds__(256) void spmm_kernel(
    const int* __restrict__ uidx, const float* __restrict__ uval,
    const int* __restrict__ iidx, const float* __restrict__ ival,
    const float* __restrict__ PT, float* __restrict__ out, int nnz)
{
    int g = blockIdx.x * 256 + threadIdx.x;
    int n = g >> 5;
    const int* idx = uidx;
    const float* val = uval;
    float* o = out;
    if (n >= nnz) {            // second matrix
        n -= nnz;
        if (n >= nnz) return;
        idx = iidx; val = ival; o += BB * AA;
    }
    int a = g & 31;
    int row = idx[n];          // index[0][n]
    int col = idx[nnz + n];    // index[1][n]
    float w = val[n];
    atomicAdd(&o[row * AA + a], w * PT[col * AA + a]);
}

extern "C" void kernel_launch(void* const* d_in, const int* in_sizes, int n_in,
                              void* d_out, int out_size, void* d_ws, size_t ws_size,
                              hipStream_t stream) {
    const int*   hist = (const int*)d_in[0];
    const float* ypos = (const float*)d_in[1];
    const int*   uidx = (const int*)d_in[3];
    const float* uval = (const float*)d_in[4];
    const int*   iidx = (const int*)d_in[5];
    const float* ival = (const float*)d_in[6];
    const float* emb  = (const float*)d_in[8];
    const float* WM   = (const float*)d_in[9];
    const float* WW   = (const float*)d_in[10];
    const float* bW   = (const float*)d_in[11];

    unsigned short* emb16 = (unsigned short*)d_ws;                   // 20 MB
    unsigned int* WMP = (unsigned int*)(emb16 + (size_t)VOCAB * DD); // 80 KB
    unsigned int* V16 = WMP + (DD / 2) * DD;                         // 12 MB
    float* PT = (float*)(V16 + (size_t)RR * (DD / 2));               // 3.84 MB
    float* out = (float*)d_out;                                      // [2, B, A]

    const int nnz = in_sizes[4];

    hipMemsetAsync(d_out, 0, (size_t)out_size * sizeof(float), stream);

    cvt_f16_kernel<<<(VOCAB * DD / 4 + 255) / 256, 256, 0, stream>>>(
        emb, emb16, VOCAB * DD / 4);
    wmp_kernel<<<((DD / 2) * DD + 255) / 256, 256, 0, stream>>>(WM, WMP);
    v_gemm_kernel<<<(RR + 31) / 32, 256, 0, stream>>>(ypos, WMP, V16);
    attn_kernel<<<RR, 256, 0, stream>>>(hist, emb16, V16, WW, bW, PT);

    const int spmm_blocks = (2 * nnz * 32 + 255) / 256;
    spmm_kernel<<<spmm_blocks, 256, 0, stream>>>(uidx, uval, iidx, ival, PT, out, nnz);
}

// Round 8
// 289.821 us; speedup vs baseline: 2.4718x; 1.0226x over previous
//
#include <hip/hip_runtime.h>
#include <math.h>

#define VOCAB 50000
#define DD 200
#define AA 32
#define RR 30000
#define LL 40
#define BB 10000

typedef _Float16 half2_t __attribute__((ext_vector_type(2)));

static __device__ __forceinline__ unsigned short f2h(float f) {
    return __builtin_bit_cast(unsigned short, (_Float16)f);   // RNE
}
static __device__ __forceinline__ float hlo(unsigned int u) {
    return (float)__builtin_bit_cast(_Float16, (unsigned short)(u & 0xFFFFu));
}
static __device__ __forceinline__ float hhi(unsigned int u) {
    return (float)__builtin_bit_cast(_Float16, (unsigned short)(u >> 16));
}
static __device__ __forceinline__ unsigned int pkh(float lo, float hi) {
    return (unsigned int)f2h(lo) | ((unsigned int)f2h(hi) << 16);
}
// packed f16 dot2: acc += a.lo*b.lo + a.hi*b.hi
static __device__ __forceinline__ float dot2(unsigned int a, unsigned int b, float acc) {
#if __has_builtin(__builtin_amdgcn_fdot2)
    return __builtin_amdgcn_fdot2(__builtin_bit_cast(half2_t, a),
                                  __builtin_bit_cast(half2_t, b), acc, false);
#else
    return acc + hlo(a) * hlo(b) + hhi(a) * hhi(b);
#endif
}

// ---------------------------------------------------------------------------
// Kernel 0: convert emb table f32 -> f16 (RNE). 10M elements, streaming.
// ---------------------------------------------------------------------------
__global__ __launch_bounds__(256) void cvt_f16_kernel(
    const float* __restrict__ src, unsigned short* __restrict__ dst, int n4)
{
    int i = blockIdx.x * 256 + threadIdx.x;
    if (i >= n4) return;
    float4 f = ((const float4*)src)[i];
    ushort4 u;
    u.x = f2h(f.x); u.y = f2h(f.y); u.z = f2h(f.z); u.w = f2h(f.w);
    ((ushort4*)dst)[i] = u;
}

// ---------------------------------------------------------------------------
// Kernel 0b: pack WM pairs along e: WMP[e2*200+d] = (WM[2e2][d], WM[2e2+1][d])
// ---------------------------------------------------------------------------
__global__ __launch_bounds__(256) void wmp_kernel(
    const float* __restrict__ WM, unsigned int* __restrict__ WMP)
{
    int i = blockIdx.x * 256 + threadIdx.x;
    if (i >= (DD / 2) * DD) return;
    int e2 = i / DD, d = i - e2 * DD;
    WMP[i] = pkh(WM[(2 * e2) * DD + d], WM[(2 * e2 + 1) * DD + d]);
}

// ---------------------------------------------------------------------------
// Kernel 1: V = Y @ W_M  with f16 dot2. Y staged as packed f16 in LDS
// (cvt on the fly). Output packed f16 pairs V16[r][i] = (d=2i, d=2i+1).
// ---------------------------------------------------------------------------
__global__ __launch_bounds__(256) void v_gemm_kernel(
    const float* __restrict__ Y, const unsigned int* __restrict__ WMP,
    unsigned int* __restrict__ V16)
{
    __shared__ unsigned int yt[32 * (DD / 2)];   // 12.8 KB packed f16
    const int r0 = blockIdx.x * 32;
    const int tid = threadIdx.x;

    for (int i = tid; i < 32 * 50; i += 256) {   // 50 float4 chunks per row
        int j = i / 50, c = i - 50 * j;
        int r = r0 + j;
        float4 f = (r < RR) ? ((const float4*)(Y + (size_t)r * DD))[c]
                            : make_float4(0.f, 0.f, 0.f, 0.f);
        uint2 u = make_uint2(pkh(f.x, f.y), pkh(f.z, f.w));
        ((uint2*)yt)[i] = u;
    }
    __syncthreads();

    if (tid < DD) {
        float acc[32];
        #pragma unroll
        for (int j = 0; j < 32; ++j) acc[j] = 0.f;
        for (int e2 = 0; e2 < DD / 2; e2 += 2) {
            unsigned int w0 = WMP[e2 * DD + tid];        // coalesced
            unsigned int w1 = WMP[(e2 + 1) * DD + tid];
            #pragma unroll
            for (int j = 0; j < 32; ++j) {
                uint2 y2 = *(const uint2*)(yt + j * (DD / 2) + e2); // broadcast b64
                acc[j] = dot2(y2.x, w0, acc[j]);
                acc[j] = dot2(y2.y, w1, acc[j]);
            }
        }
        #pragma unroll
        for (int j = 0; j < 32; ++j) {
            float partner = __shfl_xor(acc[j], 1);
            int r = r0 + j;
            if (r < RR && (tid & 1) == 0)
                V16[(size_t)r * (DD / 2) + (tid >> 1)] =
                    pkh(acc[j], partner);
        }
    }
}

// ---------------------------------------------------------------------------
// Kernel 2: per-review attention -> p_t [R, A].  Register gathers + FUSED
// unnormalized softmax: wgt = exp(dx - 8) right after the dx butterfly, z
// and sum accumulated while e_j is live -> no register crosses a barrier
// (R6/R7's cross-barrier live range caused a 123 MB scratch spill).
// exp(dx-c) is shift-invariant after the final z/tot normalization.
// ---------------------------------------------------------------------------
__global__ __launch_bounds__(256, 6) void attn_kernel(
    const int* __restrict__ hist, const unsigned short* __restrict__ emb16,
    const unsigned int* __restrict__ V16, const float* __restrict__ WW,
    const float* __restrict__ bW, float* __restrict__ PT)
{
    __shared__ float zss[4][DD];   // 3200 B
    __shared__ float sws[4];
    __shared__ float zs[DD];       // 800 B

    const int r = blockIdx.x;
    const int tid = threadIdx.x;
    const int wave = tid >> 6, lane = tid & 63;
    const int half = lane >> 5, s = lane & 31;
    const bool act = (s < 25);

    // hist row (lane<40) and this lane's V chunk (dims 8s..8s+7, per-wave)
    int h = (lane < LL) ? hist[r * LL + lane] : 0;
    uint4 vq = make_uint4(0u, 0u, 0u, 0u);
    if (act) vq = ((const uint4*)(V16 + (size_t)r * (DD / 2)))[s];

    // direct register gathers: word l = wave*10 + 2j + half, j=0..4
    uint4 e0, e1, e2, e3, e4;
    const uint4 zq = make_uint4(0u, 0u, 0u, 0u);
    {
        int w;
        w = __shfl(h, wave * 10 + 0 + half);
        e0 = act ? ((const uint4*)(emb16 + (size_t)w * DD))[s] : zq;
        w = __shfl(h, wave * 10 + 2 + half);
        e1 = act ? ((const uint4*)(emb16 + (size_t)w * DD))[s] : zq;
        w = __shfl(h, wave * 10 + 4 + half);
        e2 = act ? ((const uint4*)(emb16 + (size_t)w * DD))[s] : zq;
        w = __shfl(h, wave * 10 + 6 + half);
        e3 = act ? ((const uint4*)(emb16 + (size_t)w * DD))[s] : zq;
        w = __shfl(h, wave * 10 + 8 + half);
        e4 = act ? ((const uint4*)(emb16 + (size_t)w * DD))[s] : zq;
    }

    // fused: dx butterfly -> wgt = exp(dx-8) -> z,sum accum; e_j dies here.
    float z0 = 0.f, z1 = 0.f, z2 = 0.f, z3 = 0.f,
          z4 = 0.f, z5 = 0.f, z6 = 0.f, z7 = 0.f;
    float sw = 0.f;
    #define STEP(EJ)                                                         \
    {                                                                        \
        float p = 0.f;                                                       \
        p = dot2(EJ.x, vq.x, p); p = dot2(EJ.y, vq.y, p);                    \
        p = dot2(EJ.z, vq.z, p); p = dot2(EJ.w, vq.w, p);                    \
        _Pragma("unroll")                                                    \
        for (int off = 16; off; off >>= 1) p += __shfl_xor(p, off);          \
        float wgt = __expf(p - 8.0f);  /* all 32 lanes hold dx */            \
        sw += wgt;                                                           \
        z0 += wgt * hlo(EJ.x); z1 += wgt * hhi(EJ.x);                        \
        z2 += wgt * hlo(EJ.y); z3 += wgt * hhi(EJ.y);                        \
        z4 += wgt * hlo(EJ.z); z5 += wgt * hhi(EJ.z);                        \
        z6 += wgt * hlo(EJ.w); z7 += wgt * hhi(EJ.w);                        \
    }
    STEP(e0) STEP(e1) STEP(e2) STEP(e3) STEP(e4)
    #undef STEP

    // combine the two halves (word 2j+0 and 2j+1 live in half 0/1)
    z0 += __shfl_xor(z0, 32); z1 += __shfl_xor(z1, 32);
    z2 += __shfl_xor(z2, 32); z3 += __shfl_xor(z3, 32);
    z4 += __shfl_xor(z4, 32); z5 += __shfl_xor(z5, 32);
    z6 += __shfl_xor(z6, 32); z7 += __shfl_xor(z7, 32);
    float swt = sw + __shfl_xor(sw, 32);   // this wave's 10-word weight sum
    if (half == 0 && act) {
        ((float4*)zss[wave])[2 * s]     = make_float4(z0, z1, z2, z3);
        ((float4*)zss[wave])[2 * s + 1] = make_float4(z4, z5, z6, z7);
    }
    if (lane == 0) sws[wave] = swt;
    __syncthreads();

    // normalize: zs = (sum of wave partials) / (total weight)
    if (tid < DD) {
        float tot = sws[0] + sws[1] + sws[2] + sws[3];
        zs[tid] = (zss[0][tid] + zss[1][tid] + zss[2][tid] + zss[3][tid]) / tot;
    }
    __syncthreads();

    // p_t[r][a] = z_s . W_W[a] + b_W[a]   (8 threads per aspect)
    {
        int a = tid >> 3, j = tid & 7;
        float acc = 0.f;
        for (int d = j; d < DD; d += 8) acc += zs[d] * WW[a * DD + d];
        #pragma unroll
        for (int off = 4; off; off >>= 1) acc += __shfl_xor(acc, off);
        if (j == 0) PT[r * AA + a] = acc + bW[a];
    }
}

// ---------------------------------------------------------------------------
// Kernel 3: both sparse [B,R] @ p_t [R,A] in one launch.
// 32 lanes per nnz entry (one lane per aspect column, coalesced atomics).
// ---------------------------------------------------------------------------
__global__ __launch_bounds__(256) void spmm_kernel(
    const int* __restrict__ uidx, const float* __restrict__ uval,
    const int* __restrict__ iidx, const float* __restrict__ ival,
    const float* __restrict__ PT, float* __restrict__ out, int nnz)
{
    int g = blockIdx.x * 256 + threadIdx.x;
    int n = g >> 5;
    const int* idx = uidx;
    const float* val = uval;
    float* o = out;
    if (n >= nnz) {            // second matrix
        n -= nnz;
        if (n >= nnz) return;
        idx = iidx; val = ival; o += BB * AA;
    }
    int a = g & 31;
    int row = idx[n];          // index[0][n]
    int col = idx[nnz + n];    // index[1][n]
    float w = val[n];
    atomicAdd(&o[row * AA + a], w * PT[col * AA + a]);
}

extern "C" void kernel_launch(void* const* d_in, const int* in_sizes, int n_in,
                              void* d_out, int out_size, void* d_ws, size_t ws_size,
                              hipStream_t stream) {
    const int*   hist = (const int*)d_in[0];
    const float* ypos = (const float*)d_in[1];
    const int*   uidx = (const int*)d_in[3];
    const float* uval = (const float*)d_in[4];
    const int*   iidx = (const int*)d_in[5];
    const float* ival = (const float*)d_in[6];
    const float* emb  = (const float*)d_in[8];
    const float* WM   = (const float*)d_in[9];
    const float* WW   = (const float*)d_in[10];
    const float* bW   = (const float*)d_in[11];

    unsigned short* emb16 = (unsigned short*)d_ws;                   // 20 MB
    unsigned int* WMP = (unsigned int*)(emb16 + (size_t)VOCAB * DD); // 80 KB
    unsigned int* V16 = WMP + (DD / 2) * DD;                         // 12 MB
    float* PT = (float*)(V16 + (size_t)RR * (DD / 2));               // 3.84 MB
    float* out = (float*)d_out;                                      // [2, B, A]

    const int nnz = in_sizes[4];

    hipMemsetAsync(d_out, 0, (size_t)out_size * sizeof(float), stream);

    cvt_f16_kernel<<<(VOCAB * DD / 4 + 255) / 256, 256, 0, stream>>>(
        emb, emb16, VOCAB * DD / 4);
    wmp_kernel<<<((DD / 2) * DD + 255) / 256, 256, 0, stream>>>(WM, WMP);
    v_gemm_kernel<<<(RR + 31) / 32, 256, 0, stream>>>(ypos, WMP, V16);
    attn_kernel<<<RR, 256, 0, stream>>>(hist, emb16, V16, WW, bW, PT);

    const int spmm_blocks = (2 * nnz * 32 + 255) / 256;
    spmm_kernel<<<spmm_blocks, 256, 0, stream>>>(uidx, uval, iidx, ival, PT, out, nnz);
}